// Round 1
// baseline (246.572 us; speedup 1.0000x reference)
//
#include <hip/hip_runtime.h>
#include <hip/hip_bf16.h>

// Problem constants
// B=8, H=64, W=64, C=256, NUM_HEADS=8, dph=32, DILATION=3, KERNEL=3, k2=9
// qkv GEMM: Y[M,768] = X[M,256] @ W[768,256]^T, M = nb*4096 per chunk.

#define TM 64
#define TN 64
#define TK 32

__global__ __launch_bounds__(256) void qkv_gemm(const float* __restrict__ A,
                                                const float* __restrict__ Wq,
                                                float* __restrict__ Y,
                                                int M) {
    __shared__ float As[TK][TM + 4];  // pad 4 keeps float4 alignment, breaks bank stride
    __shared__ float Bs[TK][TN + 4];

    const int t = threadIdx.x;          // 0..255
    const int n0 = blockIdx.x * TN;     // 0..768-64
    const int m0 = blockIdx.y * TM;
    const int tx = t & 15;              // n micro
    const int ty = t >> 4;              // m micro

    float acc[4][4] = {};

    for (int k0 = 0; k0 < 256; k0 += TK) {
        __syncthreads();  // protect previous iter's reads
#pragma unroll
        for (int r = 0; r < 2; ++r) {
            int idx = t + r * 256;      // 0..511
            int row = idx >> 3;         // 0..63
            int kq  = idx & 7;          // float4 index along k
            float4 av = *(const float4*)&A[(size_t)(m0 + row) * 256 + k0 + kq * 4];
            As[kq * 4 + 0][row] = av.x;
            As[kq * 4 + 1][row] = av.y;
            As[kq * 4 + 2][row] = av.z;
            As[kq * 4 + 3][row] = av.w;
            float4 bv = *(const float4*)&Wq[(size_t)(n0 + row) * 256 + k0 + kq * 4];
            Bs[kq * 4 + 0][row] = bv.x;
            Bs[kq * 4 + 1][row] = bv.y;
            Bs[kq * 4 + 2][row] = bv.z;
            Bs[kq * 4 + 3][row] = bv.w;
        }
        __syncthreads();
#pragma unroll
        for (int kk = 0; kk < TK; ++kk) {
            float4 a = *(const float4*)&As[kk][ty * 4];
            float4 b = *(const float4*)&Bs[kk][tx * 4];
            float av4[4] = {a.x, a.y, a.z, a.w};
            float bv4[4] = {b.x, b.y, b.z, b.w};
#pragma unroll
            for (int i = 0; i < 4; ++i)
#pragma unroll
                for (int j = 0; j < 4; ++j)
                    acc[i][j] = fmaf(av4[i], bv4[j], acc[i][j]);
        }
    }

#pragma unroll
    for (int i = 0; i < 4; ++i) {
        float4 o = make_float4(acc[i][0], acc[i][1], acc[i][2], acc[i][3]);
        *(float4*)&Y[(size_t)(m0 + ty * 4 + i) * 768 + n0 + tx * 4] = o;
    }
}

// One (pixel, head) per 32-lane group; lane = d (dim-per-head channel).
// qkv layout: [bl*4096 + h*64 + w][768], o = s*256 + head*32 + d.
// Zero padding: OOB neighbor => k=0 (logit contribution 0, still in softmax), v=0.
__global__ __launch_bounds__(256) void attn_kernel(const float* __restrict__ qkv,
                                                   float* __restrict__ out,
                                                   int b0) {
    const float scale = 0.17677669529663689f;  // 1/sqrt(32)
    const int g = blockIdx.x * 8 + (threadIdx.x >> 5);
    const int d = threadIdx.x & 31;

    const int bl   = g >> 15;          // local batch
    const int rem  = g & 32767;
    const int head = rem >> 12;
    const int pix  = rem & 4095;
    const int h = pix >> 6;
    const int w = pix & 63;

    const size_t pbase = ((size_t)(bl * 64 + h) * 64 + w) * 768;
    const int co = head * 32 + d;

    const float qd = qkv[pbase + co];

    float s[9];
    float vv[9];
#pragma unroll
    for (int i = 0; i < 3; ++i) {
#pragma unroll
        for (int j = 0; j < 3; ++j) {
            const int kk = i * 3 + j;
            const int hh = h + (i - 1) * 3;
            const int ww = w + (j - 1) * 3;
            float kd = 0.f, vd = 0.f;
            if (hh >= 0 && hh < 64 && ww >= 0 && ww < 64) {
                const size_t nb = ((size_t)(bl * 64 + hh) * 64 + ww) * 768 + co;
                kd = qkv[nb + 256];
                vd = qkv[nb + 512];
            }
            float p = qd * kd;
            p += __shfl_xor(p, 16, 32);
            p += __shfl_xor(p, 8, 32);
            p += __shfl_xor(p, 4, 32);
            p += __shfl_xor(p, 2, 32);
            p += __shfl_xor(p, 1, 32);
            s[kk] = p * scale;
            vv[kk] = vd;
        }
    }

    float m = s[0];
#pragma unroll
    for (int kk = 1; kk < 9; ++kk) m = fmaxf(m, s[kk]);
    float denom = 0.f, acc = 0.f;
#pragma unroll
    for (int kk = 0; kk < 9; ++kk) {
        float e = __expf(s[kk] - m);
        denom += e;
        acc = fmaf(e, vv[kk], acc);
    }

    out[(((size_t)(b0 + bl) * 64 + h) * 64 + w) * 256 + co] = acc / denom;
}

extern "C" void kernel_launch(void* const* d_in, const int* in_sizes, int n_in,
                              void* d_out, int out_size, void* d_ws, size_t ws_size,
                              hipStream_t stream) {
    const float* x  = (const float*)d_in[0];   // [8,64,64,256]
    const float* Wq = (const float*)d_in[1];   // [768,256]
    float* out = (float*)d_out;                // [8,64,64,256]
    float* ws  = (float*)d_ws;                 // qkv chunk [nb*4096, 768]

    const size_t per_batch_f = (size_t)4096 * 768;           // floats per batch
    const size_t per_batch_b = per_batch_f * sizeof(float);  // 12.58 MB

    int bper = (int)(ws_size / per_batch_b);
    if (bper > 8) bper = 8;
    if (bper < 1) bper = 1;  // assume ws holds at least one batch

    for (int b0 = 0; b0 < 8; b0 += bper) {
        int nb = (8 - b0 < bper) ? (8 - b0) : bper;
        int M = nb * 4096;
        dim3 ggrid(768 / TN, M / TM);
        qkv_gemm<<<ggrid, 256, 0, stream>>>(x + (size_t)b0 * 4096 * 256, Wq, ws, M);
        int groups = nb * 32768;  // (bl, head, pix)
        attn_kernel<<<groups / 8, 256, 0, stream>>>(ws, out, b0);
    }
}

// Round 2
// 61.329 us; speedup vs baseline: 4.0205x; 4.0205x over previous
//
#include <hip/hip_runtime.h>
#include <hip/hip_bf16.h>

// B=8, H=64, W=64, C=256, NUM_HEADS=8, dph=32, DIL=3, k2=9
// qkv GEMM: Y[32768,768] = X[32768,256] @ W[768,256]^T in bf16 MFMA.
// ws layout (ushort units): xb[8388608] | wb[196608] | qkv[25165824]  (67.5 MB)

typedef unsigned short ushortT;
typedef __attribute__((ext_vector_type(8))) short short8;
typedef __attribute__((ext_vector_type(4))) float f32x4;

__device__ __forceinline__ ushortT f2b(float f) {  // RTNE f32 -> bf16 bits
    unsigned u = __float_as_uint(f);
    return (ushortT)((u + 0x7fffu + ((u >> 16) & 1u)) >> 16);
}
__device__ __forceinline__ float b2f(ushortT u) {
    return __uint_as_float((unsigned)u << 16);
}

// ---- convert x [8388608 f32] and W [196608 f32] to bf16 ----
__global__ __launch_bounds__(256) void to_bf16(const float* __restrict__ x,
                                               const float* __restrict__ wq,
                                               ushortT* __restrict__ xb,
                                               ushortT* __restrict__ wb) {
    const int N4X = 2097152, N4W = 49152;
    int i = blockIdx.x * 256 + threadIdx.x;
    if (i < N4X) {
        float4 f = ((const float4*)x)[i];
        ushort4 u = {f2b(f.x), f2b(f.y), f2b(f.z), f2b(f.w)};
        ((ushort4*)xb)[i] = u;
    } else {
        int j = i - N4X;
        if (j < N4W) {
            float4 f = ((const float4*)wq)[j];
            ushort4 u = {f2b(f.x), f2b(f.y), f2b(f.z), f2b(f.w)};
            ((ushort4*)wb)[j] = u;
        }
    }
}

// ---- bf16 MFMA GEMM: 128x128 tile, BK=64, 4 waves (2x2), 16x16x32 MFMA ----
// LDS: As/Bs [128 rows][64 k] bf16, 16B-slot XOR swizzle: slot' = slot ^ (row&7).
// global_load_lds writes linearly; the SOURCE address carries the inverse swizzle.
__global__ __launch_bounds__(256) void gemm_qkv(const ushortT* __restrict__ A,
                                                const ushortT* __restrict__ Bw,
                                                ushortT* __restrict__ Y) {
    __shared__ __align__(16) ushortT As[128 * 64];
    __shared__ __align__(16) ushortT Bs[128 * 64];

    // XCD-chunked swizzle: 1536 blocks, 8 XCDs, 192 per XCD (bijective).
    int bid = blockIdx.x;
    int swz = (bid & 7) * 192 + (bid >> 3);
    int mblk = swz / 6, nblk = swz - mblk * 6;
    const int m0 = mblk * 128, n0 = nblk * 128;

    const int t = threadIdx.x;
    const int lane = t & 63, wv = t >> 6;
    const int wm = (wv >> 1) * 64, wn = (wv & 1) * 64;
    const int lr = lane & 15, g = lane >> 4;
    const int srow = t >> 3, sslot = t & 7;      // staging: row within 32-row strip, 16B slot
    const int wvbase = (t & ~63) * 8;            // wave-uniform LDS base (ushort units): wv*512

    f32x4 acc[4][4] = {};

    for (int k0 = 0; k0 < 256; k0 += 64) {
        __syncthreads();
#pragma unroll
        for (int r = 0; r < 4; ++r) {
            int row = r * 32 + srow;
            int ss = sslot ^ (row & 7);
            const ushortT* ga = A + (size_t)(m0 + row) * 256 + k0 + ss * 8;
            const ushortT* gb = Bw + (size_t)(n0 + row) * 256 + k0 + ss * 8;
            __builtin_amdgcn_global_load_lds(
                (const __attribute__((address_space(1))) unsigned int*)ga,
                (__attribute__((address_space(3))) unsigned int*)(As + r * 2048 + wvbase),
                16, 0, 0);
            __builtin_amdgcn_global_load_lds(
                (const __attribute__((address_space(1))) unsigned int*)gb,
                (__attribute__((address_space(3))) unsigned int*)(Bs + r * 2048 + wvbase),
                16, 0, 0);
        }
        __syncthreads();  // compiler drains vmcnt before barrier

#pragma unroll
        for (int ksub = 0; ksub < 2; ++ksub) {
            short8 af[4], bfr[4];
#pragma unroll
            for (int mi = 0; mi < 4; ++mi) {
                int row = wm + mi * 16 + lr;
                int slot = (ksub * 4 + g) ^ (row & 7);
                af[mi] = *(const short8*)&As[row * 64 + slot * 8];
            }
#pragma unroll
            for (int ni = 0; ni < 4; ++ni) {
                int row = wn + ni * 16 + lr;
                int slot = (ksub * 4 + g) ^ (row & 7);
                bfr[ni] = *(const short8*)&Bs[row * 64 + slot * 8];
            }
#pragma unroll
            for (int mi = 0; mi < 4; ++mi)
#pragma unroll
                for (int ni = 0; ni < 4; ++ni)
                    acc[mi][ni] = __builtin_amdgcn_mfma_f32_16x16x32_bf16(
                        af[mi], bfr[ni], acc[mi][ni], 0, 0, 0);
        }
    }

    // C/D layout: col = lane&15, row = (lane>>4)*4 + reg
#pragma unroll
    for (int mi = 0; mi < 4; ++mi)
#pragma unroll
        for (int ni = 0; ni < 4; ++ni) {
            int col = n0 + wn + ni * 16 + lr;
#pragma unroll
            for (int rg = 0; rg < 4; ++rg) {
                int row = m0 + wm + mi * 16 + g * 4 + rg;
                Y[(size_t)row * 768 + col] = f2b(acc[mi][ni][rg]);
            }
        }
}

// ---- attention: one wave per pixel; lane owns 4 channels (head = lane>>3) ----
__global__ __launch_bounds__(256) void attn2(const ushortT* __restrict__ qkv,
                                             float* __restrict__ out) {
    const float scale = 0.17677669529663689f;  // 1/sqrt(32)
    const int wid = (blockIdx.x * 256 + threadIdx.x) >> 6;  // pixel 0..32767
    const int l = threadIdx.x & 63;
    const int b = wid >> 12, pix = wid & 4095;
    const int h = pix >> 6, w = pix & 63;

    const size_t pbase = (size_t)wid * 768;
    ushort4 qu = *(const ushort4*)&qkv[pbase + l * 4];
    const float q0 = b2f(qu.x), q1 = b2f(qu.y), q2 = b2f(qu.z), q3 = b2f(qu.w);

    float s[9];
    ushort4 vu[9];
#pragma unroll
    for (int i = 0; i < 3; ++i) {
#pragma unroll
        for (int j = 0; j < 3; ++j) {
            const int kk = i * 3 + j;
            const int hh = h + (i - 1) * 3;
            const int ww = w + (j - 1) * 3;
            float p = 0.f;
            ushort4 z = {0, 0, 0, 0};
            vu[kk] = z;
            if ((unsigned)hh < 64u && (unsigned)ww < 64u) {  // wave-uniform branch
                const size_t nb = ((size_t)((b << 12) + (hh << 6) + ww)) * 768;
                ushort4 ku = *(const ushort4*)&qkv[nb + 256 + l * 4];
                vu[kk] = *(const ushort4*)&qkv[nb + 512 + l * 4];
                p = q0 * b2f(ku.x) + q1 * b2f(ku.y) + q2 * b2f(ku.z) + q3 * b2f(ku.w);
            }
            p += __shfl_xor(p, 1);
            p += __shfl_xor(p, 2);
            p += __shfl_xor(p, 4);  // 8-lane (one head) reduce
            s[kk] = p * scale;
        }
    }

    float m = s[0];
#pragma unroll
    for (int kk = 1; kk < 9; ++kk) m = fmaxf(m, s[kk]);
    float denom = 0.f;
    float o0 = 0.f, o1 = 0.f, o2 = 0.f, o3 = 0.f;
#pragma unroll
    for (int kk = 0; kk < 9; ++kk) {
        float e = __expf(s[kk] - m);
        denom += e;
        o0 = fmaf(e, b2f(vu[kk].x), o0);
        o1 = fmaf(e, b2f(vu[kk].y), o1);
        o2 = fmaf(e, b2f(vu[kk].z), o2);
        o3 = fmaf(e, b2f(vu[kk].w), o3);
    }
    const float inv = 1.0f / denom;
    float4 o = make_float4(o0 * inv, o1 * inv, o2 * inv, o3 * inv);
    *(float4*)&out[(size_t)wid * 256 + l * 4] = o;
}

extern "C" void kernel_launch(void* const* d_in, const int* in_sizes, int n_in,
                              void* d_out, int out_size, void* d_ws, size_t ws_size,
                              hipStream_t stream) {
    const float* x  = (const float*)d_in[0];   // [8,64,64,256]
    const float* Wq = (const float*)d_in[1];   // [768,256]
    float* out = (float*)d_out;                // [8,64,64,256]

    ushortT* xb  = (ushortT*)d_ws;             // [32768,256]
    ushortT* wb  = xb + (size_t)8388608;       // [768,256]
    ushortT* qkv = wb + (size_t)196608;        // [32768,768]

    to_bf16<<<8384, 256, 0, stream>>>(x, Wq, xb, wb);
    gemm_qkv<<<1536, 256, 0, stream>>>(xb, wb, qkv);
    attn2<<<8192, 256, 0, stream>>>(qkv, out);
}